// Round 4
// baseline (319.026 us; speedup 1.0000x reference)
//
#include <hip/hip_runtime.h>

// SSIM (window=8 box sums) over 96 images of 512x512 fp32.
// v9 (resubmit -- round 3 failed on container acquisition, kernel never ran):
// barrier-free wave-per-strip structure.
//  - v8 post-mortem: VGPR 72 -> HW allocates 128/wave (quantized at 64/128/256)
//    -> 4 blocks/CU resident (measured 4.2); barriers couple waves; the LDS
//    round-trip (32 b128 DS ops/block-row) is a ~23 us standing floor.
//  - v9: one 64-thread wave per strip, 8 cols/lane.  Horizontal window needs
//    only lane+1 -> single __shfl_down, NO LDS, NO barriers.  3072 fully
//    independent waves (12/CU, all resident).
//  - register ring dropped: outgoing row re-loaded from cache (loaded 8 rows
//    earlier, 32 KB/wave window -> L1/L2 hit).  Frees 64 VGPR.
//  - depth-1 prefetch of next iteration's incoming+outgoing rows.
//  - arithmetic order matches v8 exactly (vs=(vs-o)+c etc), absmax-safe.
// Tripwires: WRITE_SIZE >> 96 KB => spill (v7 lesson); VGPR must be <= 128.

#define W 512
#define H 512
#define OW 505
#define OH 505
#define TH 16
#define NSTRIP ((OH + TH - 1) / TH)   // 32
#define NIMG 96
#define NPIX (96.0 * 505.0 * 505.0)   // 24482400

__device__ __forceinline__ float4 ld4(const float* p) { return *(const float4*)p; }

__global__ void finalize(const double* p, float* out) {
    out[0] = 1.0f - (float)(*p / NPIX);
}

// unpack two float4s into a float[8]
#define UNPACK8(a0, a1, dst) {                                            \
        dst[0] = a0.x; dst[1] = a0.y; dst[2] = a0.z; dst[3] = a0.w;       \
        dst[4] = a1.x; dst[5] = a1.y; dst[6] = a1.z; dst[7] = a1.w;       \
    }

__global__ void __launch_bounds__(64, 4)
ssim_main(const float* __restrict__ gt, const float* __restrict__ ni,
          double* __restrict__ acc_out)
{
    const int l   = threadIdx.x;      // 0..63
    const int c0  = l * 8;            // own cols c0..c0+7
    const int img = blockIdx.y;
    const int R0  = blockIdx.x * TH;  // first output row of strip
    const int R1  = min(R0 + TH, OH); // strip has >= 9 output rows

    const float C1 = 1e-4f;
    const float C2 = 9e-4f;

    const float* gx = gt + (size_t)img * (W * H) + c0;
    const float* gy = ni + (size_t)img * (W * H) + c0;

    // vertical 8-row window sums for own 8 columns
    float vsx[8], vsy[8], vsq[8], vsp[8];
#pragma unroll
    for (int j = 0; j < 8; ++j) { vsx[j] = 0.f; vsy[j] = 0.f; vsq[j] = 0.f; vsp[j] = 0.f; }

    // prefetch registers: incoming row (pi*), outgoing row (po*)
    float4 pix0, pix1, piy0, piy1;
    float4 pox0, pox1, poy0, poy1;

    // issue loads for row R0
    {
        const float* px = gx + (size_t)R0 * W;
        const float* py = gy + (size_t)R0 * W;
        pix0 = ld4(px); pix1 = ld4(px + 4);
        piy0 = ld4(py); piy1 = ld4(py + 4);
    }

    float acc = 0.0f;

    // ---- warmup: rows R0..R0+6, add-only; last iter prefetches row R0+7 ----
#pragma unroll 1
    for (int r = R0; r < R0 + 7; ++r) {
        float cx[8], cy[8];
        UNPACK8(pix0, pix1, cx)
        UNPACK8(piy0, piy1, cy)
        {   // issue next row's loads (row r+1 <= R0+7, always < 512)
            const float* px = gx + (size_t)(r + 1) * W;
            const float* py = gy + (size_t)(r + 1) * W;
            pix0 = ld4(px); pix1 = ld4(px + 4);
            piy0 = ld4(py); piy1 = ld4(py + 4);
        }
#pragma unroll
        for (int j = 0; j < 8; ++j) {
            vsx[j] = vsx[j] + cx[j];
            vsy[j] = vsy[j] + cy[j];
            vsq[j] = vsq[j] + (cx[j] * cx[j] + cy[j] * cy[j]);
            vsp[j] = vsp[j] + cx[j] * cy[j];
        }
    }

// horizontal sliding window + SSIM for output row; uses vs*, shuffles lane+1.
// lane 63's shuffle result is garbage but only feeds cols >= 505 (predicated).
#define HORIZ_SSIM() {                                                    \
        float nx[8], ny[8], nq[8], np_[8];                                \
        _Pragma("unroll")                                                 \
        for (int j = 0; j < 8; ++j) {                                     \
            nx[j]  = __shfl_down(vsx[j], 1);                              \
            ny[j]  = __shfl_down(vsy[j], 1);                              \
            nq[j]  = __shfl_down(vsq[j], 1);                              \
            np_[j] = __shfl_down(vsp[j], 1);                              \
        }                                                                 \
        float Sx = ((vsx[0] + vsx[1]) + (vsx[2] + vsx[3])) +              \
                   ((vsx[4] + vsx[5]) + (vsx[6] + vsx[7]));               \
        float Sy = ((vsy[0] + vsy[1]) + (vsy[2] + vsy[3])) +              \
                   ((vsy[4] + vsy[5]) + (vsy[6] + vsy[7]));               \
        float Sq = ((vsq[0] + vsq[1]) + (vsq[2] + vsq[3])) +              \
                   ((vsq[4] + vsq[5]) + (vsq[6] + vsq[7]));               \
        float Sp = ((vsp[0] + vsp[1]) + (vsp[2] + vsp[3])) +              \
                   ((vsp[4] + vsp[5]) + (vsp[6] + vsp[7]));               \
        _Pragma("unroll")                                                 \
        for (int j = 0; j < 8; ++j) {                                     \
            if (j) {                                                      \
                Sx += nx[j-1] - vsx[j-1];                                 \
                Sy += ny[j-1] - vsy[j-1];                                 \
                Sq += nq[j-1] - vsq[j-1];                                 \
                Sp += np_[j-1] - vsp[j-1];                                \
            }                                                             \
            float mu12 = Sx * Sy;                                         \
            float n1v = 2.0f * mu12 + C1;                                 \
            float n2v = 2.0f * (Sp - mu12) + C2;                          \
            float sx2 = Sx * Sx, sy2 = Sy * Sy;                           \
            float d1  = sx2 + sy2 + C1;                                   \
            float d2  = (Sq - sx2 - sy2) + C2;                            \
            float sv  = (n1v * n2v) * __builtin_amdgcn_rcpf(d1 * d2);     \
            if (c0 + j < OW) acc += sv;                                   \
        }                                                                 \
    }

    // ---- first output row o = R0 (window rows R0..R0+7), no outgoing ----
    {
        float cx[8], cy[8];
        UNPACK8(pix0, pix1, cx)
        UNPACK8(piy0, piy1, cy)
        // prefetch for o = R0+1: incoming row R0+8, outgoing row R0
        {
            const float* px = gx + (size_t)(R0 + 8) * W;
            const float* py = gy + (size_t)(R0 + 8) * W;
            pix0 = ld4(px); pix1 = ld4(px + 4);
            piy0 = ld4(py); piy1 = ld4(py + 4);
            const float* qx = gx + (size_t)R0 * W;
            const float* qy = gy + (size_t)R0 * W;
            pox0 = ld4(qx); pox1 = ld4(qx + 4);
            poy0 = ld4(qy); poy1 = ld4(qy + 4);
        }
#pragma unroll
        for (int j = 0; j < 8; ++j) {
            vsx[j] = vsx[j] + cx[j];
            vsy[j] = vsy[j] + cy[j];
            vsq[j] = vsq[j] + (cx[j] * cx[j] + cy[j] * cy[j]);
            vsp[j] = vsp[j] + cx[j] * cy[j];
        }
        HORIZ_SSIM()
    }

    // ---- main loop: o = R0+1 .. R1-1 ----
    // window rows o..o+7: add incoming row o+7 (pi*), subtract outgoing row
    // o-1 (po*).  Prefetch for o+1: incoming o+8 (<= R1+6 <= 511), outgoing o.
#pragma unroll 1
    for (int o = R0 + 1; o < R1; ++o) {
        float cx[8], cy[8], ox[8], oy[8];
        UNPACK8(pix0, pix1, cx)
        UNPACK8(piy0, piy1, cy)
        UNPACK8(pox0, pox1, ox)
        UNPACK8(poy0, poy1, oy)
        if (o + 1 < R1) {
            const float* px = gx + (size_t)(o + 8) * W;
            const float* py = gy + (size_t)(o + 8) * W;
            pix0 = ld4(px); pix1 = ld4(px + 4);
            piy0 = ld4(py); piy1 = ld4(py + 4);
            const float* qx = gx + (size_t)o * W;
            const float* qy = gy + (size_t)o * W;
            pox0 = ld4(qx); pox1 = ld4(qx + 4);
            poy0 = ld4(qy); poy1 = ld4(qy + 4);
        }
#pragma unroll
        for (int j = 0; j < 8; ++j) {
            // same arithmetic order as v8: (vs - out) + in
            vsx[j] = (vsx[j] - ox[j]) + cx[j];
            vsy[j] = (vsy[j] - oy[j]) + cy[j];
            vsq[j] = vsq[j] + ((cx[j] * cx[j] + cy[j] * cy[j]) -
                               (ox[j] * ox[j] + oy[j] * oy[j]));
            vsp[j] = vsp[j] + (cx[j] * cy[j] - ox[j] * oy[j]);
        }
        HORIZ_SSIM()
    }

    // ---- reduction: single wave -> one double atomic ----
#pragma unroll
    for (int off = 32; off > 0; off >>= 1) acc += __shfl_down(acc, off);
    if (l == 0) atomicAdd(acc_out, (double)acc);
}

extern "C" void kernel_launch(void* const* d_in, const int* in_sizes, int n_in,
                              void* d_out, int out_size, void* d_ws, size_t ws_size,
                              hipStream_t stream) {
    const float* gt = (const float*)d_in[0];
    const float* ni = (const float*)d_in[1];
    double* acc = (double*)d_ws;   // 8 bytes scratch, re-poisoned every call

    hipMemsetAsync(acc, 0, sizeof(double), stream);
    dim3 grid(NSTRIP, NIMG);
    ssim_main<<<grid, 64, 0, stream>>>(gt, ni, acc);
    finalize<<<1, 1, 0, stream>>>(acc, (float*)d_out);
}

// Round 5
// 262.060 us; speedup vs baseline: 1.2174x; 1.2174x over previous
//
#include <hip/hip_runtime.h>

// SSIM (window=8 box sums) over 96 images of 512x512 fp32.
// v10 = v9 structure (wave-per-strip, no LDS, no barriers) with the two
// counter-identified fixes:
//  - v9 post-mortem: __launch_bounds__(..,4) => effective VGPR cap 64
//    (empirical: cap = 256/min_waves; v7 and v9 both hit it) -> 203 MB spill
//    WRITE + FETCH 288 MB = 491 MB @2.76 TB/s = the whole 182 us.
//  - fix 1: __launch_bounds__(64,2) -> cap 128 >= demand (~110), no spill,
//    still 4 waves/SIMD so all 12 waves/CU resident.
//  - fix 2: XCD swizzle (T1). FETCH 288 MB == 201 MB x 23/16 strip overlap,
//    all missing L2 (adjacent strips on different XCDs under round-robin).
//    1D grid + wid=(b&7)*384+(b>>3), strip-fastest: each XCD owns 12
//    contiguous images, adjacent strips co-resident on one XCD's L2.
// Tripwires: WRITE_SIZE >> 96 KB => spill; VGPR must be <= 128.

#define W 512
#define H 512
#define OW 505
#define OH 505
#define TH 16
#define NSTRIP ((OH + TH - 1) / TH)   // 32
#define NIMG 96
#define NWG (NSTRIP * NIMG)           // 3072, divisible by 8
#define NPIX (96.0 * 505.0 * 505.0)   // 24482400

__device__ __forceinline__ float4 ld4(const float* p) { return *(const float4*)p; }

__global__ void finalize(const double* p, float* out) {
    out[0] = 1.0f - (float)(*p / NPIX);
}

// unpack two float4s into a float[8]
#define UNPACK8(a0, a1, dst) {                                            \
        dst[0] = a0.x; dst[1] = a0.y; dst[2] = a0.z; dst[3] = a0.w;       \
        dst[4] = a1.x; dst[5] = a1.y; dst[6] = a1.z; dst[7] = a1.w;       \
    }

__global__ void __launch_bounds__(64, 2)
ssim_main(const float* __restrict__ gt, const float* __restrict__ ni,
          double* __restrict__ acc_out)
{
    const int l   = threadIdx.x;      // 0..63
    const int c0  = l * 8;            // own cols c0..c0+7

    // XCD-aware swizzle: HW assigns XCD = blockIdx % 8 (round-robin).
    // wid = xcd*384 + slot, strip-fastest: adjacent strips of one image run
    // on the SAME XCD -> 7-row strip-overlap re-reads hit that XCD's L2.
    const int b     = blockIdx.x;
    const int wid   = (b & 7) * (NWG / 8) + (b >> 3);
    const int strip = wid & (NSTRIP - 1);
    const int img   = wid >> 5;

    const int R0  = strip * TH;       // first output row of strip
    const int R1  = min(R0 + TH, OH); // strip has >= 9 output rows

    const float C1 = 1e-4f;
    const float C2 = 9e-4f;

    const float* gx = gt + (size_t)img * (W * H) + c0;
    const float* gy = ni + (size_t)img * (W * H) + c0;

    // vertical 8-row window sums for own 8 columns
    float vsx[8], vsy[8], vsq[8], vsp[8];
#pragma unroll
    for (int j = 0; j < 8; ++j) { vsx[j] = 0.f; vsy[j] = 0.f; vsq[j] = 0.f; vsp[j] = 0.f; }

    // prefetch registers: incoming row (pi*), outgoing row (po*)
    float4 pix0, pix1, piy0, piy1;
    float4 pox0, pox1, poy0, poy1;

    // issue loads for row R0
    {
        const float* px = gx + (size_t)R0 * W;
        const float* py = gy + (size_t)R0 * W;
        pix0 = ld4(px); pix1 = ld4(px + 4);
        piy0 = ld4(py); piy1 = ld4(py + 4);
    }

    float acc = 0.0f;

    // ---- warmup: rows R0..R0+6, add-only; last iter prefetches row R0+7 ----
#pragma unroll 1
    for (int r = R0; r < R0 + 7; ++r) {
        float cx[8], cy[8];
        UNPACK8(pix0, pix1, cx)
        UNPACK8(piy0, piy1, cy)
        {   // issue next row's loads (row r+1 <= R0+7, always < 512)
            const float* px = gx + (size_t)(r + 1) * W;
            const float* py = gy + (size_t)(r + 1) * W;
            pix0 = ld4(px); pix1 = ld4(px + 4);
            piy0 = ld4(py); piy1 = ld4(py + 4);
        }
#pragma unroll
        for (int j = 0; j < 8; ++j) {
            vsx[j] = vsx[j] + cx[j];
            vsy[j] = vsy[j] + cy[j];
            vsq[j] = vsq[j] + (cx[j] * cx[j] + cy[j] * cy[j]);
            vsp[j] = vsp[j] + cx[j] * cy[j];
        }
    }

// horizontal sliding window + SSIM for output row; uses vs*, shuffles lane+1.
// lane 63's shuffle result is garbage but only feeds cols >= 505 (predicated).
#define HORIZ_SSIM() {                                                    \
        float nx[8], ny[8], nq[8], np_[8];                                \
        _Pragma("unroll")                                                 \
        for (int j = 0; j < 8; ++j) {                                     \
            nx[j]  = __shfl_down(vsx[j], 1);                              \
            ny[j]  = __shfl_down(vsy[j], 1);                              \
            nq[j]  = __shfl_down(vsq[j], 1);                              \
            np_[j] = __shfl_down(vsp[j], 1);                              \
        }                                                                 \
        float Sx = ((vsx[0] + vsx[1]) + (vsx[2] + vsx[3])) +              \
                   ((vsx[4] + vsx[5]) + (vsx[6] + vsx[7]));               \
        float Sy = ((vsy[0] + vsy[1]) + (vsy[2] + vsy[3])) +              \
                   ((vsy[4] + vsy[5]) + (vsy[6] + vsy[7]));               \
        float Sq = ((vsq[0] + vsq[1]) + (vsq[2] + vsq[3])) +              \
                   ((vsq[4] + vsq[5]) + (vsq[6] + vsq[7]));               \
        float Sp = ((vsp[0] + vsp[1]) + (vsp[2] + vsp[3])) +              \
                   ((vsp[4] + vsp[5]) + (vsp[6] + vsp[7]));               \
        _Pragma("unroll")                                                 \
        for (int j = 0; j < 8; ++j) {                                     \
            if (j) {                                                      \
                Sx += nx[j-1] - vsx[j-1];                                 \
                Sy += ny[j-1] - vsy[j-1];                                 \
                Sq += nq[j-1] - vsq[j-1];                                 \
                Sp += np_[j-1] - vsp[j-1];                                \
            }                                                             \
            float mu12 = Sx * Sy;                                         \
            float n1v = 2.0f * mu12 + C1;                                 \
            float n2v = 2.0f * (Sp - mu12) + C2;                          \
            float sx2 = Sx * Sx, sy2 = Sy * Sy;                           \
            float d1  = sx2 + sy2 + C1;                                   \
            float d2  = (Sq - sx2 - sy2) + C2;                            \
            float sv  = (n1v * n2v) * __builtin_amdgcn_rcpf(d1 * d2);     \
            if (c0 + j < OW) acc += sv;                                   \
        }                                                                 \
    }

    // ---- first output row o = R0 (window rows R0..R0+7), no outgoing ----
    {
        float cx[8], cy[8];
        UNPACK8(pix0, pix1, cx)
        UNPACK8(piy0, piy1, cy)
        // prefetch for o = R0+1: incoming row R0+8, outgoing row R0
        {
            const float* px = gx + (size_t)(R0 + 8) * W;
            const float* py = gy + (size_t)(R0 + 8) * W;
            pix0 = ld4(px); pix1 = ld4(px + 4);
            piy0 = ld4(py); piy1 = ld4(py + 4);
            const float* qx = gx + (size_t)R0 * W;
            const float* qy = gy + (size_t)R0 * W;
            pox0 = ld4(qx); pox1 = ld4(qx + 4);
            poy0 = ld4(qy); poy1 = ld4(qy + 4);
        }
#pragma unroll
        for (int j = 0; j < 8; ++j) {
            vsx[j] = vsx[j] + cx[j];
            vsy[j] = vsy[j] + cy[j];
            vsq[j] = vsq[j] + (cx[j] * cx[j] + cy[j] * cy[j]);
            vsp[j] = vsp[j] + cx[j] * cy[j];
        }
        HORIZ_SSIM()
    }

    // ---- main loop: o = R0+1 .. R1-1 ----
    // window rows o..o+7: add incoming row o+7 (pi*), subtract outgoing row
    // o-1 (po*).  Prefetch for o+1: incoming o+8 (<= R1+6 <= 511), outgoing o.
#pragma unroll 1
    for (int o = R0 + 1; o < R1; ++o) {
        float cx[8], cy[8], ox[8], oy[8];
        UNPACK8(pix0, pix1, cx)
        UNPACK8(piy0, piy1, cy)
        UNPACK8(pox0, pox1, ox)
        UNPACK8(poy0, poy1, oy)
        if (o + 1 < R1) {
            const float* px = gx + (size_t)(o + 8) * W;
            const float* py = gy + (size_t)(o + 8) * W;
            pix0 = ld4(px); pix1 = ld4(px + 4);
            piy0 = ld4(py); piy1 = ld4(py + 4);
            const float* qx = gx + (size_t)o * W;
            const float* qy = gy + (size_t)o * W;
            pox0 = ld4(qx); pox1 = ld4(qx + 4);
            poy0 = ld4(qy); poy1 = ld4(qy + 4);
        }
#pragma unroll
        for (int j = 0; j < 8; ++j) {
            // same arithmetic order as v8: (vs - out) + in
            vsx[j] = (vsx[j] - ox[j]) + cx[j];
            vsy[j] = (vsy[j] - oy[j]) + cy[j];
            vsq[j] = vsq[j] + ((cx[j] * cx[j] + cy[j] * cy[j]) -
                               (ox[j] * ox[j] + oy[j] * oy[j]));
            vsp[j] = vsp[j] + (cx[j] * cy[j] - ox[j] * oy[j]);
        }
        HORIZ_SSIM()
    }

    // ---- reduction: single wave -> one double atomic ----
#pragma unroll
    for (int off = 32; off > 0; off >>= 1) acc += __shfl_down(acc, off);
    if (l == 0) atomicAdd(acc_out, (double)acc);
}

extern "C" void kernel_launch(void* const* d_in, const int* in_sizes, int n_in,
                              void* d_out, int out_size, void* d_ws, size_t ws_size,
                              hipStream_t stream) {
    const float* gt = (const float*)d_in[0];
    const float* ni = (const float*)d_in[1];
    double* acc = (double*)d_ws;   // 8 bytes scratch, re-poisoned every call

    hipMemsetAsync(acc, 0, sizeof(double), stream);
    ssim_main<<<dim3(NWG), 64, 0, stream>>>(gt, ni, acc);
    finalize<<<1, 1, 0, stream>>>(acc, (float*)d_out);
}